// Round 7
// baseline (228.611 us; speedup 1.0000x reference)
//
#include <hip/hip_runtime.h>
#include <hip/hip_bf16.h>

// Problem constants
#define B_SZ 2
#define LSEQ 1024
#define DIN  2048
#define DST  16
#define DTR  64
#define KTOT 96              // DTR + 2*DST
#define NROW (B_SZ * LSEQ)   // 2048 (b,l) rows
#define NCH  64              // number of L-chunks
#define TCH  16              // timesteps per chunk (LSEQ / NCH)
#define KSP  32              // K-splits in k_proj (64 K each)

// bf16 (as ushort) -> float
__device__ __forceinline__ float b2f(unsigned int u) {
    union { unsigned int i; float f; } v;
    v.i = (u & 0xffffu) << 16;
    return v.f;
}

// scalar load: element i of a buffer that is either fp32 or bf16
__device__ __forceinline__ float ldf(const void* p, size_t i, bool f32) {
    return f32 ? ((const float*)p)[i] : b2f(((const unsigned short*)p)[i]);
}

// 4 consecutive elements as float4, dual dtype
__device__ __forceinline__ float4 ld4(const void* p, size_t i, bool f32) {
    if (f32) return *(const float4*)((const float*)p + i);
    const uint2 u = *(const uint2*)((const unsigned short*)p + i);
    float4 v;
    v.x = b2f(u.x); v.y = b2f(u.x >> 16);
    v.z = b2f(u.y); v.w = b2f(u.y >> 16);
    return v;
}

__device__ __forceinline__ float softplus_f(float v) {
    return (v > 20.f) ? v : log1pf(__expf(v));
}

// ---------------------------------------------------------------------------
// Kernel 0: dtype detector. flag=1 -> fp32, flag=0 -> bf16.
// ---------------------------------------------------------------------------
__global__ __launch_bounds__(256) void k_detect(const void* __restrict__ x,
                                                int* __restrict__ flag) {
    __shared__ int cnt;
    if (threadIdx.x == 0) cnt = 0;
    __syncthreads();
    const unsigned short* u = (const unsigned short*)x;
    int my = 0;
    for (int i = threadIdx.x; i < 4096; i += 256) {
        unsigned short v = u[2 * i];
        float af = fabsf(b2f(v));
        if (v == 0 || (af >= 6.0e-8f && af <= 1.7e7f)) my++;
    }
    atomicAdd(&cnt, my);
    __syncthreads();
    if (threadIdx.x == 0) *flag = (cnt < 2048) ? 1 : 0;
}

// ---------------------------------------------------------------------------
// Kernel 1: input projection, tiled split-K GEMM.
// C[2048][96] = x[2048][2048] . Wx^T. Tile 64 rows x 96 cols x 64 K.
// ---------------------------------------------------------------------------
__global__ __launch_bounds__(256, 4) void k_proj(
    const void* __restrict__ x,      // [NROW][DIN]
    const void* __restrict__ Wx,     // [96][DIN]
    const int*  __restrict__ flag,
    float* __restrict__ part)        // [KSP][NROW][96]
{
    const bool f32 = (*flag != 0);
    __shared__ float lx[32][68];     // [k][row], padded
    __shared__ float lw[32][100];    // [k][col], padded
    const int tid = threadIdx.x;
    const int bx = blockIdx.x;       // row group (64 rows)
    const int by = blockIdx.y;       // K-split (64 K)
    const int rt = tid >> 4, ct = tid & 15;
    const int r0 = rt * 4, c0 = ct * 6;

    float acc[4][6];
    #pragma unroll
    for (int i = 0; i < 4; i++)
        #pragma unroll
        for (int k = 0; k < 6; k++) acc[i][k] = 0.f;

    for (int half = 0; half < 2; half++) {
        const int k0 = by * 64 + half * 32;
        #pragma unroll
        for (int it = 0; it < 2; it++) {
            const int idx = tid + it * 256;
            const int r = idx >> 3, q = idx & 7;
            float4 v = ld4(x, (size_t)(bx * 64 + r) * DIN + k0 + q * 4, f32);
            lx[q * 4 + 0][r] = v.x; lx[q * 4 + 1][r] = v.y;
            lx[q * 4 + 2][r] = v.z; lx[q * 4 + 3][r] = v.w;
        }
        #pragma unroll
        for (int it = 0; it < 3; it++) {
            const int idx = tid + it * 256;
            const int c = idx >> 3, q = idx & 7;
            float4 v = ld4(Wx, (size_t)c * DIN + k0 + q * 4, f32);
            lw[q * 4 + 0][c] = v.x; lw[q * 4 + 1][c] = v.y;
            lw[q * 4 + 2][c] = v.z; lw[q * 4 + 3][c] = v.w;
        }
        __syncthreads();

        #pragma unroll 4
        for (int j = 0; j < 32; j++) {
            const float4 xa = *(const float4*)&lx[j][r0];
            const float2 w0 = *(const float2*)&lw[j][c0];
            const float2 w1 = *(const float2*)&lw[j][c0 + 2];
            const float2 w2 = *(const float2*)&lw[j][c0 + 4];
            const float xr[4] = {xa.x, xa.y, xa.z, xa.w};
            const float wc[6] = {w0.x, w0.y, w1.x, w1.y, w2.x, w2.y};
            #pragma unroll
            for (int i = 0; i < 4; i++)
                #pragma unroll
                for (int k = 0; k < 6; k++)
                    acc[i][k] += xr[i] * wc[k];
        }
        __syncthreads();
    }

    float* p = part + ((size_t)by * NROW + bx * 64 + r0) * KTOT + c0;
    #pragma unroll
    for (int i = 0; i < 4; i++) {
        float* row = p + (size_t)i * KTOT;
        *(float2*)(row)     = make_float2(acc[i][0], acc[i][1]);
        *(float2*)(row + 2) = make_float2(acc[i][2], acc[i][3]);
        *(float2*)(row + 4) = make_float2(acc[i][4], acc[i][5]);
    }
}

// ---------------------------------------------------------------------------
// Kernel 2: combine K-split partials -> drw / Bin / Cin.
// ---------------------------------------------------------------------------
__global__ __launch_bounds__(256, 4) void k_comb(
    const float* __restrict__ part,
    float* __restrict__ drw, float* __restrict__ Bin, float* __restrict__ Cin)
{
    const int idx = blockIdx.x * 256 + threadIdx.x;   // < NROW*96
    float s = 0.f;
    #pragma unroll 8
    for (int ks = 0; ks < KSP; ks++)
        s += part[(size_t)ks * NROW * KTOT + idx];
    const int r = idx / KTOT, c = idx % KTOT;
    if (c < DTR)            drw[r * DTR + c] = s;
    else if (c < DTR + DST) Bin[r * DST + (c - DTR)] = s;
    else                    Cin[r * DST + (c - DTR - DST)] = s;
}

// ---------------------------------------------------------------------------
// Kernel 3 (scan phase 1, fused dt, SCALAR-PIPE uniform operands).
// Round-6 post-mortem: traffic fixed but ~42 us of the 55 us dispatch was
// LDS-pipe serialization: 256 ds_read_b128 (drw_lds re-read per kq*r) + 256
// ds_read_b32 (Bs broadcasts) per thread. All those reads are WAVE-UNIFORM
// (indices from blockIdx + loop counters), so they now come straight from
// const __restrict__ global memory -> compiler emits s_load on the free
// scalar pipe (SGPR operand into v_fma). drw_lds/Bs deleted. x_lds/dt_lds
// (genuinely per-thread, 2 b32 per t) stay. dt-dot no longer touches LDS, so
// it overlaps the in-flight x staging before the single barrier.
// LDS: x 16K + dt 16K = 32.25 KB -> 4 blocks/CU.
// ---------------------------------------------------------------------------
__global__ __launch_bounds__(256, 2) void k_scan1(
    const void* __restrict__ x,
    const float* __restrict__ drw,   // [NROW][DTR]
    const float* __restrict__ Bin,
    const void* __restrict__ Wdt,    // [DIN][DTR]
    const void* __restrict__ bdt,    // [DIN]
    const void* __restrict__ Alog,
    const int*  __restrict__ flag,
    float* __restrict__ Pb,          // [B][NCH][DST][DIN]
    float* __restrict__ Hb)
{
    const bool f32 = (*flag != 0);
    __shared__ float x_lds[TCH][256];
    __shared__ float dt_lds[TCH][256];
    const int tid = threadIdx.x;
    const int d = blockIdx.x * 256 + tid;
    const int c = blockIdx.y;
    const int b = blockIdx.z;
    const int row0 = b * LSEQ + c * TCH;

    // ---- stage x chunk [16 t][256 d], coalesced float4 (in flight during dt) ----
    #pragma unroll
    for (int it = 0; it < 4; it++) {
        const int f4 = tid + it * 256;           // < 1024
        const int t  = f4 >> 6, q4 = f4 & 63;
        float4 v = ld4(x, (size_t)(row0 + t) * DIN + blockIdx.x * 256 + q4 * 4, f32);
        *(float4*)&x_lds[t][q4 * 4] = v;
    }

    float A[DST];
    #pragma unroll
    for (int sq = 0; sq < DST / 4; sq++) {
        float4 av = ld4(Alog, (size_t)d * DST + sq * 4, f32);
        A[sq * 4 + 0] = -__expf(av.x); A[sq * 4 + 1] = -__expf(av.y);
        A[sq * 4 + 2] = -__expf(av.z); A[sq * 4 + 3] = -__expf(av.w);
    }

    // ---- fused dt: drw operand is wave-uniform -> scalar loads ----
    {
        float dtv[TCH];
        const float bd = ldf(bdt, (size_t)d, f32);
        #pragma unroll
        for (int r = 0; r < TCH; r++) dtv[r] = bd;
        #pragma unroll 4
        for (int kq = 0; kq < DTR / 4; kq++) {
            const float4 w = ld4(Wdt, (size_t)d * DTR + kq * 4, f32);
            #pragma unroll
            for (int r = 0; r < TCH; r++) {
                const float4 a = *(const float4*)(drw + (size_t)(row0 + r) * DTR + kq * 4);
                dtv[r] += a.x * w.x; dtv[r] += a.y * w.y;
                dtv[r] += a.z * w.z; dtv[r] += a.w * w.w;
            }
        }
        #pragma unroll
        for (int r = 0; r < TCH; r++) dt_lds[r][tid] = softplus_f(dtv[r]);
    }
    __syncthreads();   // x_lds cross-thread; dt_lds is own-column (safe)

    float P[DST], H[DST];
    #pragma unroll
    for (int s = 0; s < DST; s++) { P[s] = 1.f; H[s] = 0.f; }

    #pragma unroll 1
    for (int t = 0; t < TCH; t++) {
        const float dtv_t = dt_lds[t][tid];
        const float xv    = x_lds[t][tid];
        const float u     = dtv_t * xv;
        const float* brow = Bin + (size_t)(row0 + t) * DST;   // uniform -> s_load
        const float4 b0 = *(const float4*)(brow);
        const float4 b1 = *(const float4*)(brow + 4);
        const float4 b2 = *(const float4*)(brow + 8);
        const float4 b3 = *(const float4*)(brow + 12);
        const float bsv[16] = {b0.x, b0.y, b0.z, b0.w, b1.x, b1.y, b1.z, b1.w,
                               b2.x, b2.y, b2.z, b2.w, b3.x, b3.y, b3.z, b3.w};
        #pragma unroll
        for (int s = 0; s < DST; s++) {
            const float e = __expf(dtv_t * A[s]);
            P[s] *= e;
            H[s] = e * H[s] + u * bsv[s];
        }
    }

    const size_t base = (size_t)(b * NCH + c) * DST * DIN + d;
    #pragma unroll
    for (int s = 0; s < DST; s++) {
        Pb[base + (size_t)s * DIN] = P[s];
        Hb[base + (size_t)s * DIN] = H[s];
    }
}

// ---------------------------------------------------------------------------
// Kernel 4 (scan phase 2): cross-chunk exclusive scan per (b,s,d).
// ---------------------------------------------------------------------------
__global__ __launch_bounds__(256, 4) void k_scan2(
    const float* __restrict__ Pb,
    const float* __restrict__ Hb,
    float* __restrict__ hin)
{
    const int idx = blockIdx.x * 256 + threadIdx.x;
    const int b   = idx / (DST * DIN);
    const int rem = idx % (DST * DIN);
    float h = 0.f;
    #pragma unroll 4
    for (int c = 0; c < NCH; c++) {
        const size_t o = (size_t)(b * NCH + c) * DST * DIN + rem;
        const float p = Pb[o], hb = Hb[o];
        hin[o] = h;
        h = hb + p * h;
    }
}

// ---------------------------------------------------------------------------
// Kernel 5 (scan phase 3, fused dt, SCALAR-PIPE uniform operands): seeded
// with hin, emit y. Same restructure as k_scan1; B and C rows via s_load.
// dt computed identically to k_scan1 -> bitwise-consistent across phases.
// ---------------------------------------------------------------------------
__global__ __launch_bounds__(256, 2) void k_scan3(
    const void* __restrict__ x,
    const float* __restrict__ drw,
    const float* __restrict__ Bin,
    const float* __restrict__ Cin,
    const void* __restrict__ Wdt,
    const void* __restrict__ bdt,
    const void* __restrict__ Alog,
    const void* __restrict__ Dv,
    const float* __restrict__ hin,
    const int*  __restrict__ flag,
    void* __restrict__ y)
{
    const bool f32 = (*flag != 0);
    __shared__ float x_lds[TCH][256];
    __shared__ float dt_lds[TCH][256];
    const int tid = threadIdx.x;
    const int d = blockIdx.x * 256 + tid;
    const int c = blockIdx.y;
    const int b = blockIdx.z;
    const int row0 = b * LSEQ + c * TCH;

    #pragma unroll
    for (int it = 0; it < 4; it++) {
        const int f4 = tid + it * 256;
        const int t  = f4 >> 6, q4 = f4 & 63;
        float4 v = ld4(x, (size_t)(row0 + t) * DIN + blockIdx.x * 256 + q4 * 4, f32);
        *(float4*)&x_lds[t][q4 * 4] = v;
    }

    float A[DST];
    #pragma unroll
    for (int sq = 0; sq < DST / 4; sq++) {
        float4 av = ld4(Alog, (size_t)d * DST + sq * 4, f32);
        A[sq * 4 + 0] = -__expf(av.x); A[sq * 4 + 1] = -__expf(av.y);
        A[sq * 4 + 2] = -__expf(av.z); A[sq * 4 + 3] = -__expf(av.w);
    }
    const float Dd = ldf(Dv, (size_t)d, f32);

    {
        float dtv[TCH];
        const float bd = ldf(bdt, (size_t)d, f32);
        #pragma unroll
        for (int r = 0; r < TCH; r++) dtv[r] = bd;
        #pragma unroll 4
        for (int kq = 0; kq < DTR / 4; kq++) {
            const float4 w = ld4(Wdt, (size_t)d * DTR + kq * 4, f32);
            #pragma unroll
            for (int r = 0; r < TCH; r++) {
                const float4 a = *(const float4*)(drw + (size_t)(row0 + r) * DTR + kq * 4);
                dtv[r] += a.x * w.x; dtv[r] += a.y * w.y;
                dtv[r] += a.z * w.z; dtv[r] += a.w * w.w;
            }
        }
        #pragma unroll
        for (int r = 0; r < TCH; r++) dt_lds[r][tid] = softplus_f(dtv[r]);
    }

    float h[DST];
    const size_t base = (size_t)(b * NCH + c) * DST * DIN + d;
    #pragma unroll
    for (int s = 0; s < DST; s++) h[s] = hin[base + (size_t)s * DIN];
    __syncthreads();   // x_lds cross-thread

    #pragma unroll 1
    for (int t = 0; t < TCH; t++) {
        const float dtv_t = dt_lds[t][tid];
        const float xv    = x_lds[t][tid];
        const float u     = dtv_t * xv;
        const float* brow = Bin + (size_t)(row0 + t) * DST;   // uniform -> s_load
        const float* crow = Cin + (size_t)(row0 + t) * DST;   // uniform -> s_load
        const float4 b0 = *(const float4*)(brow);
        const float4 b1 = *(const float4*)(brow + 4);
        const float4 b2 = *(const float4*)(brow + 8);
        const float4 b3 = *(const float4*)(brow + 12);
        const float4 c0v = *(const float4*)(crow);
        const float4 c1v = *(const float4*)(crow + 4);
        const float4 c2v = *(const float4*)(crow + 8);
        const float4 c3v = *(const float4*)(crow + 12);
        const float bsv[16] = {b0.x, b0.y, b0.z, b0.w, b1.x, b1.y, b1.z, b1.w,
                               b2.x, b2.y, b2.z, b2.w, b3.x, b3.y, b3.z, b3.w};
        const float csv[16] = {c0v.x, c0v.y, c0v.z, c0v.w, c1v.x, c1v.y, c1v.z, c1v.w,
                               c2v.x, c2v.y, c2v.z, c2v.w, c3v.x, c3v.y, c3v.z, c3v.w};
        float yv = Dd * xv;
        #pragma unroll
        for (int s = 0; s < DST; s++) {
            const float e = __expf(dtv_t * A[s]);
            h[s] = e * h[s] + u * bsv[s];
            yv += h[s] * csv[s];
        }
        const size_t off = (size_t)(row0 + t) * DIN + d;
        if (f32) ((float*)y)[off] = yv;
        else     ((__hip_bfloat16*)y)[off] = __float2bfloat16(yv);
    }
}

// ---------------------------------------------------------------------------
extern "C" void kernel_launch(void* const* d_in, const int* in_sizes, int n_in,
                              void* d_out, int out_size, void* d_ws, size_t ws_size,
                              hipStream_t stream) {
    const void* x    = d_in[0];
    const void* Wx   = d_in[1];
    const void* Wdt  = d_in[2];
    const void* bdt  = d_in[3];
    const void* Alog = d_in[4];
    const void* Dv   = d_in[5];

    // ---- workspace layout, NO aliasing (~77 MB; ws is >=268 MB) ----
    int*   flag  = (int*)d_ws;
    float* basep = (float*)d_ws + 16;
    float* drw   = basep;                                  // NROW*DTR   = 131072
    float* Bin   = drw + (size_t)NROW * DTR;               // NROW*DST   = 32768
    float* Cin   = Bin + (size_t)NROW * DST;               // NROW*DST   = 32768
    float* part  = Cin + (size_t)NROW * DST;               // KSP*NROW*96 = 6291456
    float* Pb    = part + (size_t)KSP * NROW * KTOT;       // B*NCH*DST*DIN = 4194304
    float* Hb    = Pb + (size_t)B_SZ * NCH * DST * DIN;    // 4194304
    float* hin   = Hb + (size_t)B_SZ * NCH * DST * DIN;    // 4194304

    k_detect<<<1, 256, 0, stream>>>(x, flag);

    k_proj<<<dim3(NROW / 64, KSP), 256, 0, stream>>>(x, Wx, flag, part);

    k_comb<<<(NROW * KTOT) / 256, 256, 0, stream>>>(part, drw, Bin, Cin);

    dim3 g1(DIN / 256, NCH, B_SZ);
    k_scan1<<<g1, 256, 0, stream>>>(x, drw, Bin, Wdt, bdt, Alog, flag, Pb, Hb);

    k_scan2<<<(B_SZ * DST * DIN) / 256, 256, 0, stream>>>(Pb, Hb, hin);

    k_scan3<<<g1, 256, 0, stream>>>(x, drw, Bin, Cin, Wdt, bdt, Alog, Dv, hin, flag, d_out);
}

// Round 8
// 183.923 us; speedup vs baseline: 1.2430x; 1.2430x over previous
//
#include <hip/hip_runtime.h>
#include <hip/hip_bf16.h>

// Problem constants
#define B_SZ 2
#define LSEQ 1024
#define DIN  2048
#define DST  16
#define DTR  64
#define KTOT 96              // DTR + 2*DST
#define NROW (B_SZ * LSEQ)   // 2048 (b,l) rows
#define NCH  64              // number of L-chunks
#define TCH  16              // timesteps per chunk (LSEQ / NCH)
#define KSP  32              // K-splits in k_proj (64 K each)

// bf16 (as ushort) -> float
__device__ __forceinline__ float b2f(unsigned int u) {
    union { unsigned int i; float f; } v;
    v.i = (u & 0xffffu) << 16;
    return v.f;
}

// scalar load: element i of a buffer that is either fp32 or bf16
__device__ __forceinline__ float ldf(const void* p, size_t i, bool f32) {
    return f32 ? ((const float*)p)[i] : b2f(((const unsigned short*)p)[i]);
}

// 4 consecutive elements as float4, dual dtype
__device__ __forceinline__ float4 ld4(const void* p, size_t i, bool f32) {
    if (f32) return *(const float4*)((const float*)p + i);
    const uint2 u = *(const uint2*)((const unsigned short*)p + i);
    float4 v;
    v.x = b2f(u.x); v.y = b2f(u.x >> 16);
    v.z = b2f(u.y); v.w = b2f(u.y >> 16);
    return v;
}

__device__ __forceinline__ float softplus_f(float v) {
    return (v > 20.f) ? v : log1pf(__expf(v));
}

// ---------------------------------------------------------------------------
// Kernel 0: dtype detector. flag=1 -> fp32, flag=0 -> bf16.
// ---------------------------------------------------------------------------
__global__ __launch_bounds__(256) void k_detect(const void* __restrict__ x,
                                                int* __restrict__ flag) {
    __shared__ int cnt;
    if (threadIdx.x == 0) cnt = 0;
    __syncthreads();
    const unsigned short* u = (const unsigned short*)x;
    int my = 0;
    for (int i = threadIdx.x; i < 4096; i += 256) {
        unsigned short v = u[2 * i];
        float af = fabsf(b2f(v));
        if (v == 0 || (af >= 6.0e-8f && af <= 1.7e7f)) my++;
    }
    atomicAdd(&cnt, my);
    __syncthreads();
    if (threadIdx.x == 0) *flag = (cnt < 2048) ? 1 : 0;
}

// ---------------------------------------------------------------------------
// Kernel 1: input projection, tiled split-K GEMM.
// C[2048][96] = x[2048][2048] . Wx^T. Tile 64 rows x 96 cols x 64 K.
// ---------------------------------------------------------------------------
__global__ __launch_bounds__(256, 4) void k_proj(
    const void* __restrict__ x,      // [NROW][DIN]
    const void* __restrict__ Wx,     // [96][DIN]
    const int*  __restrict__ flag,
    float* __restrict__ part)        // [KSP][NROW][96]
{
    const bool f32 = (*flag != 0);
    __shared__ float lx[32][68];     // [k][row], padded
    __shared__ float lw[32][100];    // [k][col], padded
    const int tid = threadIdx.x;
    const int bx = blockIdx.x;       // row group (64 rows)
    const int by = blockIdx.y;       // K-split (64 K)
    const int rt = tid >> 4, ct = tid & 15;
    const int r0 = rt * 4, c0 = ct * 6;

    float acc[4][6];
    #pragma unroll
    for (int i = 0; i < 4; i++)
        #pragma unroll
        for (int k = 0; k < 6; k++) acc[i][k] = 0.f;

    for (int half = 0; half < 2; half++) {
        const int k0 = by * 64 + half * 32;
        #pragma unroll
        for (int it = 0; it < 2; it++) {
            const int idx = tid + it * 256;
            const int r = idx >> 3, q = idx & 7;
            float4 v = ld4(x, (size_t)(bx * 64 + r) * DIN + k0 + q * 4, f32);
            lx[q * 4 + 0][r] = v.x; lx[q * 4 + 1][r] = v.y;
            lx[q * 4 + 2][r] = v.z; lx[q * 4 + 3][r] = v.w;
        }
        #pragma unroll
        for (int it = 0; it < 3; it++) {
            const int idx = tid + it * 256;
            const int c = idx >> 3, q = idx & 7;
            float4 v = ld4(Wx, (size_t)c * DIN + k0 + q * 4, f32);
            lw[q * 4 + 0][c] = v.x; lw[q * 4 + 1][c] = v.y;
            lw[q * 4 + 2][c] = v.z; lw[q * 4 + 3][c] = v.w;
        }
        __syncthreads();

        #pragma unroll 4
        for (int j = 0; j < 32; j++) {
            const float4 xa = *(const float4*)&lx[j][r0];
            const float2 w0 = *(const float2*)&lw[j][c0];
            const float2 w1 = *(const float2*)&lw[j][c0 + 2];
            const float2 w2 = *(const float2*)&lw[j][c0 + 4];
            const float xr[4] = {xa.x, xa.y, xa.z, xa.w};
            const float wc[6] = {w0.x, w0.y, w1.x, w1.y, w2.x, w2.y};
            #pragma unroll
            for (int i = 0; i < 4; i++)
                #pragma unroll
                for (int k = 0; k < 6; k++)
                    acc[i][k] += xr[i] * wc[k];
        }
        __syncthreads();
    }

    float* p = part + ((size_t)by * NROW + bx * 64 + r0) * KTOT + c0;
    #pragma unroll
    for (int i = 0; i < 4; i++) {
        float* row = p + (size_t)i * KTOT;
        *(float2*)(row)     = make_float2(acc[i][0], acc[i][1]);
        *(float2*)(row + 2) = make_float2(acc[i][2], acc[i][3]);
        *(float2*)(row + 4) = make_float2(acc[i][4], acc[i][5]);
    }
}

// ---------------------------------------------------------------------------
// Kernel 2: combine K-split partials -> drw / Bin / interleaved BC.
// BC[row][s][2] = {B, C} so k_scan3 fetches both with one ds_read_b64.
// ---------------------------------------------------------------------------
__global__ __launch_bounds__(256, 4) void k_comb(
    const float* __restrict__ part,
    float* __restrict__ drw, float* __restrict__ Bin, float* __restrict__ BC)
{
    const int idx = blockIdx.x * 256 + threadIdx.x;   // < NROW*96
    float s = 0.f;
    #pragma unroll 8
    for (int ks = 0; ks < KSP; ks++)
        s += part[(size_t)ks * NROW * KTOT + idx];
    const int r = idx / KTOT, c = idx % KTOT;
    if (c < DTR) {
        drw[r * DTR + c] = s;
    } else if (c < DTR + DST) {
        Bin[r * DST + (c - DTR)] = s;
        BC[(size_t)r * 2 * DST + (c - DTR) * 2] = s;
    } else {
        BC[(size_t)r * 2 * DST + (c - DTR - DST) * 2 + 1] = s;
    }
}

// ---------------------------------------------------------------------------
// Kernel 3 (NEW): dt GEMM + softplus, replaces the in-scan dt-dot.
// dt[r][d] = softplus(drw[r].Wdt[d] + bdt[d]); M=N=2048, K=64 single stage.
// Round-7 post-mortem: the fused dt-dot cost ~3k cy/wave of ds_read_b128
// broadcasts in EACH scan (LDS-pipe bound) or worse via s_load (round 7).
// Dedicated GEMM pays the fetch ONCE with 16x register reuse (4x4 tile).
// Round-3 k_dt died on 16-way staging-write conflicts ([k][68] layout);
// [64][65] pad makes staging writes bank = (4q+j+r)%32 -> <=2-way (free)
// and compute b128 reads 2-way. Expect SQ_LDS_BANK_CONFLICT ~ 0.
// ---------------------------------------------------------------------------
__global__ __launch_bounds__(256, 4) void k_dtg(
    const float* __restrict__ drw,   // [NROW][DTR] (f32 workspace)
    const void* __restrict__ Wdt,    // [DIN][DTR]
    const void* __restrict__ bdt,    // [DIN]
    const int*  __restrict__ flag,
    float* __restrict__ dt)          // [NROW][DIN]
{
    const bool f32 = (*flag != 0);
    __shared__ float la[DTR][65];    // [k][r], pad 65 -> conflict-free
    __shared__ float lb[DTR][65];    // [k][d]
    const int tid = threadIdx.x;
    const int r0g = blockIdx.x * 64, c0g = blockIdx.y * 64;

    #pragma unroll
    for (int it = 0; it < 4; it++) {
        const int idx = tid + it * 256;
        const int r = idx >> 4, q = idx & 15;
        const float4 v = *(const float4*)(drw + (size_t)(r0g + r) * DTR + q * 4);
        la[q * 4 + 0][r] = v.x; la[q * 4 + 1][r] = v.y;
        la[q * 4 + 2][r] = v.z; la[q * 4 + 3][r] = v.w;
    }
    #pragma unroll
    for (int it = 0; it < 4; it++) {
        const int idx = tid + it * 256;
        const int c = idx >> 4, q = idx & 15;
        const float4 v = ld4(Wdt, (size_t)(c0g + c) * DTR + q * 4, f32);
        lb[q * 4 + 0][c] = v.x; lb[q * 4 + 1][c] = v.y;
        lb[q * 4 + 2][c] = v.z; lb[q * 4 + 3][c] = v.w;
    }
    __syncthreads();

    const int rt = tid >> 4, ct = tid & 15;
    const int r0 = rt * 4, c0 = ct * 4;
    float acc[4][4];
    #pragma unroll
    for (int i = 0; i < 4; i++)
        #pragma unroll
        for (int k = 0; k < 4; k++) acc[i][k] = 0.f;

    #pragma unroll 4
    for (int k = 0; k < DTR; k++) {
        const float4 a = *(const float4*)&la[k][r0];
        const float4 bq = *(const float4*)&lb[k][c0];
        const float ar[4] = {a.x, a.y, a.z, a.w};
        const float bc[4] = {bq.x, bq.y, bq.z, bq.w};
        #pragma unroll
        for (int i = 0; i < 4; i++)
            #pragma unroll
            for (int j = 0; j < 4; j++)
                acc[i][j] += ar[i] * bc[j];
    }

    float bd[4];
    #pragma unroll
    for (int j = 0; j < 4; j++) bd[j] = ldf(bdt, (size_t)(c0g + c0 + j), f32);
    #pragma unroll
    for (int i = 0; i < 4; i++) {
        float4 o;
        o.x = softplus_f(acc[i][0] + bd[0]);
        o.y = softplus_f(acc[i][1] + bd[1]);
        o.z = softplus_f(acc[i][2] + bd[2]);
        o.w = softplus_f(acc[i][3] + bd[3]);
        *(float4*)(dt + (size_t)(r0g + r0 + i) * DIN + c0g + c0) = o;
    }
}

// ---------------------------------------------------------------------------
// Kernel 4 (scan phase 1): chunk-local scan, dt PRECOMPUTED (k_dtg).
// Per t: 2 own-column b32 (x, dt) + 16 b32 broadcasts (B) + 16 exp + FMAs.
// P computed as exp(A[s] * sum(dt)) instead of a 16-product chain.
// LDS 33.25 KB -> 4 blocks/CU. t-loop unroll 1 (round-5 spill lesson).
// ---------------------------------------------------------------------------
__global__ __launch_bounds__(256, 2) void k_scan1(
    const void* __restrict__ x,
    const float* __restrict__ dtg,   // [NROW][DIN] precomputed dt
    const float* __restrict__ Bin,
    const void* __restrict__ Alog,
    const int*  __restrict__ flag,
    float* __restrict__ Pb,          // [B][NCH][DST][DIN]
    float* __restrict__ Hb)
{
    const bool f32 = (*flag != 0);
    __shared__ float x_lds[TCH][256];
    __shared__ float dt_lds[TCH][256];
    __shared__ float Bs[TCH * DST];  // 256 floats
    const int tid = threadIdx.x;
    const int d = blockIdx.x * 256 + tid;
    const int c = blockIdx.y;
    const int b = blockIdx.z;
    const int row0 = b * LSEQ + c * TCH;

    #pragma unroll
    for (int it = 0; it < 4; it++) {
        const int f4 = tid + it * 256;           // < 1024
        const int t  = f4 >> 6, q4 = f4 & 63;
        float4 v = ld4(x, (size_t)(row0 + t) * DIN + blockIdx.x * 256 + q4 * 4, f32);
        *(float4*)&x_lds[t][q4 * 4] = v;
        float4 w = *(const float4*)(dtg + (size_t)(row0 + t) * DIN + blockIdx.x * 256 + q4 * 4);
        *(float4*)&dt_lds[t][q4 * 4] = w;
    }
    Bs[tid] = Bin[(size_t)row0 * DST + tid];     // TCH*DST == 256

    float A[DST];
    #pragma unroll
    for (int sq = 0; sq < DST / 4; sq++) {
        float4 av = ld4(Alog, (size_t)d * DST + sq * 4, f32);
        A[sq * 4 + 0] = -__expf(av.x); A[sq * 4 + 1] = -__expf(av.y);
        A[sq * 4 + 2] = -__expf(av.z); A[sq * 4 + 3] = -__expf(av.w);
    }
    __syncthreads();

    float H[DST];
    #pragma unroll
    for (int s = 0; s < DST; s++) H[s] = 0.f;
    float sdt = 0.f;

    #pragma unroll 1
    for (int t = 0; t < TCH; t++) {
        const float dtv_t = dt_lds[t][tid];
        const float xv    = x_lds[t][tid];
        const float u     = dtv_t * xv;
        sdt += dtv_t;
        const float* bs = Bs + t * DST;
        #pragma unroll
        for (int s = 0; s < DST; s++) {
            const float e = __expf(dtv_t * A[s]);
            H[s] = e * H[s] + u * bs[s];
        }
    }

    const size_t base = (size_t)(b * NCH + c) * DST * DIN + d;
    #pragma unroll
    for (int s = 0; s < DST; s++) {
        Pb[base + (size_t)s * DIN] = __expf(A[s] * sdt);
        Hb[base + (size_t)s * DIN] = H[s];
    }
}

// ---------------------------------------------------------------------------
// Kernel 5 (scan phase 2): cross-chunk exclusive scan per (b,s,d).
// ---------------------------------------------------------------------------
__global__ __launch_bounds__(256, 4) void k_scan2(
    const float* __restrict__ Pb,
    const float* __restrict__ Hb,
    float* __restrict__ hin)
{
    const int idx = blockIdx.x * 256 + threadIdx.x;
    const int b   = idx / (DST * DIN);
    const int rem = idx % (DST * DIN);
    float h = 0.f;
    #pragma unroll 4
    for (int c = 0; c < NCH; c++) {
        const size_t o = (size_t)(b * NCH + c) * DST * DIN + rem;
        const float p = Pb[o], hb = Hb[o];
        hin[o] = h;
        h = hb + p * h;
    }
}

// ---------------------------------------------------------------------------
// Kernel 6 (scan phase 3): seeded with hin, emit y. dt precomputed.
// B,C interleaved -> one b64 broadcast per (t,s): 16 ops/t, not 32.
// LDS 34.25 KB -> 4 blocks/CU.
// ---------------------------------------------------------------------------
__global__ __launch_bounds__(256, 2) void k_scan3(
    const void* __restrict__ x,
    const float* __restrict__ dtg,
    const float* __restrict__ BC,    // [NROW][DST][2]
    const void* __restrict__ Alog,
    const void* __restrict__ Dv,
    const float* __restrict__ hin,
    const int*  __restrict__ flag,
    void* __restrict__ y)
{
    const bool f32 = (*flag != 0);
    __shared__ float x_lds[TCH][256];
    __shared__ float dt_lds[TCH][256];
    __shared__ float BCs[TCH * DST][2];  // 512 floats
    const int tid = threadIdx.x;
    const int d = blockIdx.x * 256 + tid;
    const int c = blockIdx.y;
    const int b = blockIdx.z;
    const int row0 = b * LSEQ + c * TCH;

    #pragma unroll
    for (int it = 0; it < 4; it++) {
        const int f4 = tid + it * 256;
        const int t  = f4 >> 6, q4 = f4 & 63;
        float4 v = ld4(x, (size_t)(row0 + t) * DIN + blockIdx.x * 256 + q4 * 4, f32);
        *(float4*)&x_lds[t][q4 * 4] = v;
        float4 w = *(const float4*)(dtg + (size_t)(row0 + t) * DIN + blockIdx.x * 256 + q4 * 4);
        *(float4*)&dt_lds[t][q4 * 4] = w;
    }
    *(float2*)&BCs[tid][0] = *(const float2*)(BC + (size_t)row0 * 2 * DST + tid * 2);

    float A[DST];
    #pragma unroll
    for (int sq = 0; sq < DST / 4; sq++) {
        float4 av = ld4(Alog, (size_t)d * DST + sq * 4, f32);
        A[sq * 4 + 0] = -__expf(av.x); A[sq * 4 + 1] = -__expf(av.y);
        A[sq * 4 + 2] = -__expf(av.z); A[sq * 4 + 3] = -__expf(av.w);
    }
    const float Dd = ldf(Dv, (size_t)d, f32);

    float h[DST];
    const size_t base = (size_t)(b * NCH + c) * DST * DIN + d;
    #pragma unroll
    for (int s = 0; s < DST; s++) h[s] = hin[base + (size_t)s * DIN];
    __syncthreads();

    #pragma unroll 1
    for (int t = 0; t < TCH; t++) {
        const float dtv_t = dt_lds[t][tid];
        const float xv    = x_lds[t][tid];
        const float u     = dtv_t * xv;
        float yv = Dd * xv;
        #pragma unroll
        for (int s = 0; s < DST; s++) {
            const float2 bc = *(const float2*)&BCs[t * DST + s][0];
            const float e = __expf(dtv_t * A[s]);
            h[s] = e * h[s] + u * bc.x;
            yv += h[s] * bc.y;
        }
        const size_t off = (size_t)(row0 + t) * DIN + d;
        if (f32) ((float*)y)[off] = yv;
        else     ((__hip_bfloat16*)y)[off] = __float2bfloat16(yv);
    }
}

// ---------------------------------------------------------------------------
extern "C" void kernel_launch(void* const* d_in, const int* in_sizes, int n_in,
                              void* d_out, int out_size, void* d_ws, size_t ws_size,
                              hipStream_t stream) {
    const void* x    = d_in[0];
    const void* Wx   = d_in[1];
    const void* Wdt  = d_in[2];
    const void* bdt  = d_in[3];
    const void* Alog = d_in[4];
    const void* Dv   = d_in[5];

    // ---- workspace layout, NO aliasing (~94 MB; ws is >=268 MB) ----
    int*   flag  = (int*)d_ws;
    float* basep = (float*)d_ws + 16;
    float* drw   = basep;                                  // NROW*DTR      = 131072
    float* Bin   = drw + (size_t)NROW * DTR;               // NROW*DST      = 32768
    float* BC    = Bin + (size_t)NROW * DST;               // NROW*DST*2    = 65536
    float* part  = BC + (size_t)NROW * DST * 2;            // KSP*NROW*96   = 6291456
    float* dtg   = part + (size_t)KSP * NROW * KTOT;       // NROW*DIN      = 4194304
    float* Pb    = dtg + (size_t)NROW * DIN;               // B*NCH*DST*DIN = 4194304
    float* Hb    = Pb + (size_t)B_SZ * NCH * DST * DIN;    // 4194304
    float* hin   = Hb + (size_t)B_SZ * NCH * DST * DIN;    // 4194304

    k_detect<<<1, 256, 0, stream>>>(x, flag);

    k_proj<<<dim3(NROW / 64, KSP), 256, 0, stream>>>(x, Wx, flag, part);

    k_comb<<<(NROW * KTOT) / 256, 256, 0, stream>>>(part, drw, Bin, BC);

    k_dtg<<<dim3(NROW / 64, DIN / 64), 256, 0, stream>>>(drw, Wdt, bdt, flag, dtg);

    dim3 g1(DIN / 256, NCH, B_SZ);
    k_scan1<<<g1, 256, 0, stream>>>(x, dtg, Bin, Alog, flag, Pb, Hb);

    k_scan2<<<(B_SZ * DST * DIN) / 256, 256, 0, stream>>>(Pb, Hb, hin);

    k_scan3<<<g1, 256, 0, stream>>>(x, dtg, BC, Alog, Dv, hin, flag, d_out);
}